// Round 4
// baseline (213.080 us; speedup 1.0000x reference)
//
#include <hip/hip_runtime.h>

#define B_    16
#define L_    1024
#define H_    8
#define SCALE  0.17677669529663687f              // 1/sqrt(32)
#define QSCALE 0.25510940349191965f              // SCALE * log2(e)  (exp -> exp2)

typedef __attribute__((ext_vector_type(8))) short bf16x8;
typedef __attribute__((ext_vector_type(4))) float f32x4;
typedef unsigned short u16t;

__device__ inline u16t f2bf(float f) {
    unsigned u = __float_as_uint(f);
    u = (u + 0x7FFF + ((u >> 16) & 1)) >> 16;
    return (u16t)u;
}
__device__ inline unsigned f2bf_pk(float a, float b) {
    unsigned ua = __float_as_uint(a);
    unsigned ub = __float_as_uint(b);
    ua = (ua + 0x7FFF + ((ua >> 16) & 1)) >> 16;
    ub = (ub + 0x7FFF + ((ub >> 16) & 1)) >> 16;
    return ua | (ub << 16);
}
__device__ inline uint2 f2bf_pk4(float a, float b, float c, float d) {
    uint2 u; u.x = f2bf_pk(a, b); u.y = f2bf_pk(c, d); return u;
}
// truncating bf16 pack: low16 = hi(f0), high16 = hi(f1) — one v_perm_b32
__device__ inline unsigned trunc_pk(float f0, float f1) {
    return __builtin_amdgcn_perm(__float_as_uint(f1), __float_as_uint(f0), 0x07060302u);
}

// ---------------------------------------------------------------------------
// Prep: z=0 -> transpose+convert x (B,128,1024) fp32 -> xbT (B,1024,128) bf16
//       z=1 -> convert the three weight matrices fp32 -> bf16 (flat copy)
// ---------------------------------------------------------------------------
__global__ __launch_bounds__(256) void prep_kernel(
    const float* __restrict__ x, const float* __restrict__ w_qkv,
    const float* __restrict__ w_o, const float* __restrict__ w_res,
    u16t* __restrict__ xbT, u16t* __restrict__ wqb,
    u16t* __restrict__ wob, u16t* __restrict__ wrb)
{
    const int tid = threadIdx.x;
    if (blockIdx.z == 0) {
        __shared__ u16t T[64][144];
        const int b = blockIdx.y, l0 = blockIdx.x * 64;
#pragma unroll
        for (int i = 0; i < 8; i++) {
            const int c = i * 16 + (tid >> 4);
            const int l = (tid & 15) * 4;
            const float4 v = *(const float4*)(x + ((long)b * 128 + c) * 1024 + l0 + l);
            T[l + 0][c] = f2bf(v.x);
            T[l + 1][c] = f2bf(v.y);
            T[l + 2][c] = f2bf(v.z);
            T[l + 3][c] = f2bf(v.w);
        }
        __syncthreads();
#pragma unroll
        for (int i = 0; i < 4; i++) {
            const int l  = i * 16 + (tid >> 4);
            const int c0 = (tid & 15) * 8;
            *(uint4*)(xbT + ((long)b * 1024 + l0 + l) * 128 + c0) = *(const uint4*)&T[l][c0];
        }
    } else {
        const int idx = blockIdx.y * 16 + blockIdx.x;
        if (idx >= 144) return;                 // 147456 fp32 total / 1024
        const int f = idx * 1024 + tid * 4;
        const float* src; u16t* dst; int off;
        if (f < 98304)       { src = w_qkv; dst = wqb; off = f; }
        else if (f < 131072) { src = w_o;   dst = wob; off = f - 98304; }
        else                 { src = w_res; dst = wrb; off = f - 131072; }
        const float4 v = *(const float4*)(src + off);
        *(uint2*)(dst + off) = f2bf_pk4(v.x, v.y, v.z, v.w);
    }
}

// ---------------------------------------------------------------------------
// QKV GEMM: grid (x=lblk[16], y=bh[128]) -> XCD = lblk%8 (x-slice L2-resident).
// 2048 blocks = 8/CU. Wave = 96 o x 16 l, K=128 (4 fully-unrolled steps).
// Q stores fold QSCALE (softmax uses exp2). K,Q transposed [t|s][d]; V natural.
// ---------------------------------------------------------------------------
__global__ __launch_bounds__(256) void qkv_gemm_kernel(
    const u16t* __restrict__ wqb, const u16t* __restrict__ xbT,
    const float* __restrict__ b_qkv,
    u16t* __restrict__ qT, u16t* __restrict__ kT, u16t* __restrict__ vN)
{
    const int lblk = blockIdx.x * 64;
    const int bh = blockIdx.y;
    const int b = bh >> 3, h = bh & 7;
    const int tid = threadIdx.x, lane = tid & 63, wv = tid >> 6;
    const int l15 = lane & 15, quad = lane >> 4;
    const int lw = lblk + wv * 16;

    f32x4 acc[6];
#pragma unroll
    for (int mi = 0; mi < 6; mi++) acc[mi] = (f32x4)0.f;

    const u16t* wrow = wqb + (long)h * 96 * 128;
    const u16t* xrow = xbT + ((long)b * 1024 + lw + l15) * 128;
#pragma unroll
    for (int ks = 0; ks < 4; ks++) {
        const int k0 = ks * 32 + quad * 8;
        const bf16x8 bf = *(const bf16x8*)(xrow + k0);
        bf16x8 af[6];
#pragma unroll
        for (int mi = 0; mi < 6; mi++)
            af[mi] = *(const bf16x8*)(wrow + (mi * 16 + l15) * 128 + k0);
#pragma unroll
        for (int mi = 0; mi < 6; mi++)
            acc[mi] = __builtin_amdgcn_mfma_f32_16x16x32_bf16(af[mi], bf, acc[mi], 0, 0, 0);
    }

    const long bh_ = bh;
    const int l = lw + l15;
#pragma unroll
    for (int mi = 0; mi < 6; mi++) {
        float bias[4];
#pragma unroll
        for (int r = 0; r < 4; r++) bias[r] = b_qkv[h * 96 + mi * 16 + quad * 4 + r];
        const f32x4 a = acc[mi];
        if (mi < 2) {           // Q: fold QSCALE, store transposed [s][d]
            const uint2 u = f2bf_pk4((a[0] + bias[0]) * QSCALE, (a[1] + bias[1]) * QSCALE,
                                     (a[2] + bias[2]) * QSCALE, (a[3] + bias[3]) * QSCALE);
            *(uint2*)(qT + (bh_ * 1024 + l) * 32 + mi * 16 + quad * 4) = u;
        } else if (mi < 4) {    // K: store transposed [t][d]
            const uint2 u = f2bf_pk4(a[0] + bias[0], a[1] + bias[1],
                                     a[2] + bias[2], a[3] + bias[3]);
            *(uint2*)(kT + (bh_ * 1024 + l) * 32 + (mi - 2) * 16 + quad * 4) = u;
        } else {                // V: store natural [d][t]
#pragma unroll
            for (int r = 0; r < 4; r++)
                vN[(bh_ * 32 + (mi - 4) * 16 + quad * 4 + r) * 1024 + l] = f2bf(a[r] + bias[r]);
        }
    }
}

// ---------------------------------------------------------------------------
// Attention: grid (x=bh[128], y=sblk[16]) -> XCD = h; K/V (2 MB/head-set)
// stay L2-resident per XCD. 2048 blocks = 8/CU; wave = 16 s (one tile).
// Explicit next-iter K/V prefetch; exp2; v_perm truncating P pack;
// P LDS round-trip is wave-private (no barriers).
// ---------------------------------------------------------------------------
__global__ __launch_bounds__(256) void attn_kernel3(
    const u16t* __restrict__ qT, const u16t* __restrict__ kT,
    const u16t* __restrict__ vN, u16t* __restrict__ zT)
{
    __shared__ __align__(16) u16t Ps[4][16][40];

    const int bh = blockIdx.x;
    const int b = bh >> 3, h = bh & 7;
    const int sblk = blockIdx.y * 64;
    const int tid = threadIdx.x, lane = tid & 63, wv = tid >> 6;
    const int l15 = lane & 15, quad = lane >> 4;

    const int s = sblk + wv * 16 + l15;
    const bf16x8 qf = *(const bf16x8*)(qT + ((long)bh * 1024 + s) * 32 + quad * 8);

    const u16t* kp = kT + (long)bh * 1024 * 32 + l15 * 32 + quad * 8;
    const u16t* vp = vN + (long)bh * 32 * 1024 + l15 * 1024 + quad * 8;

    f32x4 zacc0 = (f32x4)0.f, zacc1 = (f32x4)0.f;
    float lacc = 0.f;

    bf16x8 kf0 = *(const bf16x8*)(kp);
    bf16x8 kf1 = *(const bf16x8*)(kp + 16 * 32);
    bf16x8 vf0 = *(const bf16x8*)(vp);
    bf16x8 vf1 = *(const bf16x8*)(vp + 16 * 1024);

    for (int t0 = 0; t0 < L_; t0 += 32) {
        const int tn = (t0 + 32) & 1023;        // wraps on last iter (discarded)
        const bf16x8 nk0 = *(const bf16x8*)(kp + tn * 32);
        const bf16x8 nk1 = *(const bf16x8*)(kp + tn * 32 + 16 * 32);
        const bf16x8 nv0 = *(const bf16x8*)(vp + tn);
        const bf16x8 nv1 = *(const bf16x8*)(vp + tn + 16 * 1024);

        const f32x4 s0 = __builtin_amdgcn_mfma_f32_16x16x32_bf16(kf0, qf, (f32x4)0.f, 0, 0, 0);
        const f32x4 s1 = __builtin_amdgcn_mfma_f32_16x16x32_bf16(kf1, qf, (f32x4)0.f, 0, 0, 0);
        f32x4 e0, e1;
#pragma unroll
        for (int i = 0; i < 4; i++) {
            e0[i] = __builtin_amdgcn_exp2f(s0[i]);
            e1[i] = __builtin_amdgcn_exp2f(s1[i]);
        }
        lacc += (e0[0] + e0[1]) + (e0[2] + e0[3]) + (e1[0] + e1[1]) + (e1[2] + e1[3]);

        uint2 u;
        u.x = trunc_pk(e0[0], e0[1]);
        u.y = trunc_pk(e0[2], e0[3]);
        *(uint2*)&Ps[wv][l15][quad * 4] = u;
        u.x = trunc_pk(e1[0], e1[1]);
        u.y = trunc_pk(e1[2], e1[3]);
        *(uint2*)&Ps[wv][l15][16 + quad * 4] = u;

        const bf16x8 pf = *(const bf16x8*)&Ps[wv][l15][quad * 8];
        zacc0 = __builtin_amdgcn_mfma_f32_16x16x32_bf16(vf0, pf, zacc0, 0, 0, 0);
        zacc1 = __builtin_amdgcn_mfma_f32_16x16x32_bf16(vf1, pf, zacc1, 0, 0, 0);

        kf0 = nk0; kf1 = nk1; vf0 = nv0; vf1 = nv1;
    }

    float lf = lacc;
    lf += __shfl_xor(lf, 16);
    lf += __shfl_xor(lf, 32);
    const float rl = 1.f / lf;                   // lane-local: s = l15-based

    u16t* zrow = zT + ((long)b * 1024 + s) * 256 + h * 32;
    uint2 u0 = f2bf_pk4(zacc0[0] * rl, zacc0[1] * rl, zacc0[2] * rl, zacc0[3] * rl);
    *(uint2*)(zrow + quad * 4) = u0;
    uint2 u1 = f2bf_pk4(zacc1[0] * rl, zacc1[1] * rl, zacc1[2] * rl, zacc1[3] * rl);
    *(uint2*)(zrow + 16 + quad * 4) = u1;
}

// ---------------------------------------------------------------------------
// Fused output GEMM: out = w_o @ z + w_res @ x + b_o + b_res  (K = 256 + 128)
// grid (x=lblk[32], y=oblk[2], z=b[16]) = 1024 blocks = 4/CU.
// Block = 64 o x 32 l; wave = 32 o x 16 l; K fully unrolled (12 steps).
// ---------------------------------------------------------------------------
__global__ __launch_bounds__(256) void out_gemm_kernel(
    const u16t* __restrict__ wob, const u16t* __restrict__ wrb,
    const u16t* __restrict__ zT, const u16t* __restrict__ xbT,
    const float* __restrict__ b_o, const float* __restrict__ b_res,
    float* __restrict__ out)
{
    const int lblk = blockIdx.x * 32, oblk = blockIdx.y * 64, b = blockIdx.z;
    const int tid = threadIdx.x, lane = tid & 63, wv = tid >> 6;
    const int wm = wv >> 1, wn = wv & 1;
    const int l15 = lane & 15, quad = lane >> 4;
    const int ow = oblk + wm * 32;
    const int lw = lblk + wn * 16;

    f32x4 acc0 = (f32x4)0.f, acc1 = (f32x4)0.f;

    const u16t* zrow = zT + ((long)b * 1024 + lw + l15) * 256;
    const u16t* xrow = xbT + ((long)b * 1024 + lw + l15) * 128;

#pragma unroll
    for (int ks = 0; ks < 8; ks++) {           // z part, K=256
        const int k0 = ks * 32 + quad * 8;
        const bf16x8 af0 = *(const bf16x8*)(wob + (ow + l15) * 256 + k0);
        const bf16x8 af1 = *(const bf16x8*)(wob + (ow + 16 + l15) * 256 + k0);
        const bf16x8 bf  = *(const bf16x8*)(zrow + k0);
        acc0 = __builtin_amdgcn_mfma_f32_16x16x32_bf16(af0, bf, acc0, 0, 0, 0);
        acc1 = __builtin_amdgcn_mfma_f32_16x16x32_bf16(af1, bf, acc1, 0, 0, 0);
    }
#pragma unroll
    for (int ks = 0; ks < 4; ks++) {           // x part, K=128
        const int k0 = ks * 32 + quad * 8;
        const bf16x8 af0 = *(const bf16x8*)(wrb + (ow + l15) * 128 + k0);
        const bf16x8 af1 = *(const bf16x8*)(wrb + (ow + 16 + l15) * 128 + k0);
        const bf16x8 bf  = *(const bf16x8*)(xrow + k0);
        acc0 = __builtin_amdgcn_mfma_f32_16x16x32_bf16(af0, bf, acc0, 0, 0, 0);
        acc1 = __builtin_amdgcn_mfma_f32_16x16x32_bf16(af1, bf, acc1, 0, 0, 0);
    }

    const int lcol = lw + l15;
#pragma unroll
    for (int mi = 0; mi < 2; mi++) {
        const f32x4 a = (mi == 0) ? acc0 : acc1;
#pragma unroll
        for (int r = 0; r < 4; r++) {
            const int o = ow + mi * 16 + quad * 4 + r;
            out[((long)b * 128 + o) * 1024 + lcol] = a[r] + b_o[o] + b_res[o];
        }
    }
}

// ---------------------------------------------------------------------------
extern "C" void kernel_launch(void* const* d_in, const int* in_sizes, int n_in,
                              void* d_out, int out_size, void* d_ws, size_t ws_size,
                              hipStream_t stream)
{
    const float* x     = (const float*)d_in[0];
    const float* w_qkv = (const float*)d_in[1];
    const float* b_qkv = (const float*)d_in[2];
    const float* w_o   = (const float*)d_in[3];
    const float* b_o   = (const float*)d_in[4];
    const float* w_res = (const float*)d_in[5];
    const float* b_res = (const float*)d_in[6];
    float* out = (float*)d_out;

    u16t* xbT = (u16t*)d_ws;                   // [B][1024][128]
    u16t* qT  = xbT + (size_t)2097152;         // [B][H][1024][32]
    u16t* kT  = qT  + (size_t)4194304;         // [B][H][1024][32]
    u16t* vN  = kT  + (size_t)4194304;         // [B][H][32][1024]
    u16t* zT  = vN  + (size_t)4194304;         // [B][1024][256]
    u16t* wqb = zT  + (size_t)4194304;         // [768][128]
    u16t* wob = wqb + (size_t)98304;           // [128][256]
    u16t* wrb = wob + (size_t)32768;           // [128][128]

    prep_kernel<<<dim3(16, 16, 2), 256, 0, stream>>>(x, w_qkv, w_o, w_res, xbT, wqb, wob, wrb);
    qkv_gemm_kernel<<<dim3(16, 128, 1), 256, 0, stream>>>(wqb, xbT, b_qkv, qT, kT, vN);
    attn_kernel3<<<dim3(128, 16, 1), 256, 0, stream>>>(qT, kT, vN, zT);
    out_gemm_kernel<<<dim3(32, 2, 16), 256, 0, stream>>>(wob, wrb, zT, xbT, b_o, b_res, out);
}

// Round 5
// 156.995 us; speedup vs baseline: 1.3572x; 1.3572x over previous
//
#include <hip/hip_runtime.h>

#define B_    16
#define L_    1024
#define H_    8
#define SCALE  0.17677669529663687f              // 1/sqrt(32)
#define QSCALE 0.25510940349191965f              // SCALE * log2(e)  (exp -> exp2)

typedef __attribute__((ext_vector_type(8))) short bf16x8;
typedef __attribute__((ext_vector_type(4))) float f32x4;
typedef unsigned short u16t;

__device__ inline u16t f2bf(float f) {
    unsigned u = __float_as_uint(f);
    u = (u + 0x7FFF + ((u >> 16) & 1)) >> 16;
    return (u16t)u;
}
__device__ inline unsigned f2bf_pk(float a, float b) {
    unsigned ua = __float_as_uint(a);
    unsigned ub = __float_as_uint(b);
    ua = (ua + 0x7FFF + ((ua >> 16) & 1)) >> 16;
    ub = (ub + 0x7FFF + ((ub >> 16) & 1)) >> 16;
    return ua | (ub << 16);
}
__device__ inline uint2 f2bf_pk4(float a, float b, float c, float d) {
    uint2 u; u.x = f2bf_pk(a, b); u.y = f2bf_pk(c, d); return u;
}
// truncating bf16 pack: low16 = hi(f0), high16 = hi(f1) — one v_perm_b32
__device__ inline unsigned trunc_pk(float f0, float f1) {
    return __builtin_amdgcn_perm(__float_as_uint(f1), __float_as_uint(f0), 0x07060302u);
}

// ---------------------------------------------------------------------------
// Prep: z=0 -> transpose+convert x (B,128,1024) fp32 -> xbT (B,1024,128) bf16
//       z=1 -> convert the three weight matrices fp32 -> bf16 (flat copy)
// ---------------------------------------------------------------------------
__global__ __launch_bounds__(256) void prep_kernel(
    const float* __restrict__ x, const float* __restrict__ w_qkv,
    const float* __restrict__ w_o, const float* __restrict__ w_res,
    u16t* __restrict__ xbT, u16t* __restrict__ wqb,
    u16t* __restrict__ wob, u16t* __restrict__ wrb)
{
    const int tid = threadIdx.x;
    if (blockIdx.z == 0) {
        __shared__ u16t T[64][144];
        const int b = blockIdx.y, l0 = blockIdx.x * 64;
#pragma unroll
        for (int i = 0; i < 8; i++) {
            const int c = i * 16 + (tid >> 4);
            const int l = (tid & 15) * 4;
            const float4 v = *(const float4*)(x + ((long)b * 128 + c) * 1024 + l0 + l);
            T[l + 0][c] = f2bf(v.x);
            T[l + 1][c] = f2bf(v.y);
            T[l + 2][c] = f2bf(v.z);
            T[l + 3][c] = f2bf(v.w);
        }
        __syncthreads();
#pragma unroll
        for (int i = 0; i < 4; i++) {
            const int l  = i * 16 + (tid >> 4);
            const int c0 = (tid & 15) * 8;
            *(uint4*)(xbT + ((long)b * 1024 + l0 + l) * 128 + c0) = *(const uint4*)&T[l][c0];
        }
    } else {
        const int idx = blockIdx.y * 16 + blockIdx.x;
        if (idx >= 144) return;
        const int f = idx * 1024 + tid * 4;
        const float* src; u16t* dst; int off;
        if (f < 98304)       { src = w_qkv; dst = wqb; off = f; }
        else if (f < 131072) { src = w_o;   dst = wob; off = f - 98304; }
        else                 { src = w_res; dst = wrb; off = f - 131072; }
        const float4 v = *(const float4*)(src + off);
        *(uint2*)(dst + off) = f2bf_pk4(v.x, v.y, v.z, v.w);
    }
}

// ---------------------------------------------------------------------------
// QKV GEMM (R2/R3 config): block = (lblk 128, bh). Wave: 96 o x 32 l,
// K=128 (4 unrolled steps, 12 independent MFMAs each).
// Q folds QSCALE; Q,K stored transposed [s|t][d]; V natural [d][t].
// ---------------------------------------------------------------------------
__global__ __launch_bounds__(256) void qkv_gemm_kernel(
    const u16t* __restrict__ wqb, const u16t* __restrict__ xbT,
    const float* __restrict__ b_qkv,
    u16t* __restrict__ qT, u16t* __restrict__ kT, u16t* __restrict__ vN)
{
    const int lblk = blockIdx.x * 128;
    const int bh = blockIdx.y;
    const int b = bh >> 3, h = bh & 7;
    const int tid = threadIdx.x, lane = tid & 63, wv = tid >> 6;
    const int l15 = lane & 15, quad = lane >> 4;
    const int lw = lblk + wv * 32;

    f32x4 acc[6][2];
#pragma unroll
    for (int mi = 0; mi < 6; mi++)
#pragma unroll
        for (int ni = 0; ni < 2; ni++) acc[mi][ni] = (f32x4)0.f;

    const u16t* wrow = wqb + (long)h * 96 * 128;
#pragma unroll
    for (int ks = 0; ks < 4; ks++) {
        const int k0 = ks * 32 + quad * 8;
        bf16x8 af[6], bf[2];
#pragma unroll
        for (int mi = 0; mi < 6; mi++)
            af[mi] = *(const bf16x8*)(wrow + (mi * 16 + l15) * 128 + k0);
#pragma unroll
        for (int ni = 0; ni < 2; ni++)
            bf[ni] = *(const bf16x8*)(xbT + ((long)b * 1024 + lw + ni * 16 + l15) * 128 + k0);
#pragma unroll
        for (int mi = 0; mi < 6; mi++)
#pragma unroll
            for (int ni = 0; ni < 2; ni++)
                acc[mi][ni] = __builtin_amdgcn_mfma_f32_16x16x32_bf16(af[mi], bf[ni], acc[mi][ni], 0, 0, 0);
    }

    const long bh_ = bh;
#pragma unroll
    for (int mi = 0; mi < 6; mi++) {
        float bias[4];
#pragma unroll
        for (int r = 0; r < 4; r++) bias[r] = b_qkv[h * 96 + mi * 16 + quad * 4 + r];
#pragma unroll
        for (int ni = 0; ni < 2; ni++) {
            const int l = lw + ni * 16 + l15;
            const f32x4 a = acc[mi][ni];
            if (mi < 2) {           // Q: fold QSCALE, transposed [s][d]
                const uint2 u = f2bf_pk4((a[0] + bias[0]) * QSCALE, (a[1] + bias[1]) * QSCALE,
                                         (a[2] + bias[2]) * QSCALE, (a[3] + bias[3]) * QSCALE);
                *(uint2*)(qT + (bh_ * 1024 + l) * 32 + mi * 16 + quad * 4) = u;
            } else if (mi < 4) {    // K: transposed [t][d]
                const uint2 u = f2bf_pk4(a[0] + bias[0], a[1] + bias[1],
                                         a[2] + bias[2], a[3] + bias[3]);
                *(uint2*)(kT + (bh_ * 1024 + l) * 32 + (mi - 2) * 16 + quad * 4) = u;
            } else {                // V: natural [d][t]
#pragma unroll
                for (int r = 0; r < 4; r++)
                    vN[(bh_ * 32 + (mi - 4) * 16 + quad * 4 + r) * 1024 + l] = f2bf(a[r] + bias[r]);
            }
        }
    }
}

// ---------------------------------------------------------------------------
// Attention R5: grid (x=bh -> XCD=h, y=sblk[8]); 1024 blocks = 4/CU.
// Wave = 32 s (2 s-tiles); iterate 64 t (2 t-tiles) per loop:
// 4 independent (st,tt) chains, each with private Ps buffer. All QK/exp/
// pack/ds_write issue before any ds_read -> DS latency buried under VALU.
// ---------------------------------------------------------------------------
__global__ __launch_bounds__(256) void attn_kernel5(
    const u16t* __restrict__ qT, const u16t* __restrict__ kT,
    const u16t* __restrict__ vN, u16t* __restrict__ zT)
{
    __shared__ __align__(16) u16t Ps[4][2][2][16][40];   // [wv][st][tt][s-row][32t+pad]

    const int bh = blockIdx.x;
    const int b = bh >> 3, h = bh & 7;
    const int sblk = blockIdx.y * 128;
    const int tid = threadIdx.x, lane = tid & 63, wv = tid >> 6;
    const int l15 = lane & 15, quad = lane >> 4;

    const int sw = sblk + wv * 32;
    bf16x8 qf[2];
    qf[0] = *(const bf16x8*)(qT + ((long)bh * 1024 + sw + l15) * 32 + quad * 8);
    qf[1] = *(const bf16x8*)(qT + ((long)bh * 1024 + sw + 16 + l15) * 32 + quad * 8);

    const u16t* kp = kT + (long)bh * 1024 * 32 + l15 * 32 + quad * 8;
    const u16t* vp = vN + (long)bh * 32 * 1024 + l15 * 1024 + quad * 8;

    f32x4 zacc[2][2];                // [st][dt]
#pragma unroll
    for (int a = 0; a < 2; a++)
#pragma unroll
        for (int c = 0; c < 2; c++) zacc[a][c] = (f32x4)0.f;
    f32x4 lacc4[2] = {(f32x4)0.f, (f32x4)0.f};

    for (int t0 = 0; t0 < L_; t0 += 64) {
        // K fragments for 4 t-groups (t = t0 + tg*16 + l15)
        bf16x8 kf[4], vf[2][2];      // vf[dt][tt]
#pragma unroll
        for (int tg = 0; tg < 4; tg++)
            kf[tg] = *(const bf16x8*)(kp + (t0 + tg * 16) * 32);
#pragma unroll
        for (int dt = 0; dt < 2; dt++)
#pragma unroll
            for (int tt = 0; tt < 2; tt++)
                vf[dt][tt] = *(const bf16x8*)(vp + dt * 16 * 1024 + t0 + tt * 32);

        // phase 1: all QK MFMAs + exp + pack + LDS writes (8 chains' worth)
#pragma unroll
        for (int st = 0; st < 2; st++) {
#pragma unroll
            for (int tg = 0; tg < 4; tg++) {
                const f32x4 sv = __builtin_amdgcn_mfma_f32_16x16x32_bf16(kf[tg], qf[st], (f32x4)0.f, 0, 0, 0);
                f32x4 ev;
#pragma unroll
                for (int i = 0; i < 4; i++) ev[i] = __builtin_amdgcn_exp2f(sv[i]);
                lacc4[st] += ev;
                uint2 u;
                u.x = trunc_pk(ev[0], ev[1]);
                u.y = trunc_pk(ev[2], ev[3]);
                *(uint2*)&Ps[wv][st][tg >> 1][l15][(tg & 1) * 16 + quad * 4] = u;
            }
        }

        // phase 2: P reads + PV MFMAs (reads of earliest writes are long-retired)
#pragma unroll
        for (int st = 0; st < 2; st++) {
#pragma unroll
            for (int tt = 0; tt < 2; tt++) {
                const bf16x8 pf = *(const bf16x8*)&Ps[wv][st][tt][l15][quad * 8];
                zacc[st][0] = __builtin_amdgcn_mfma_f32_16x16x32_bf16(vf[0][tt], pf, zacc[st][0], 0, 0, 0);
                zacc[st][1] = __builtin_amdgcn_mfma_f32_16x16x32_bf16(vf[1][tt], pf, zacc[st][1], 0, 0, 0);
            }
        }
    }

#pragma unroll
    for (int st = 0; st < 2; st++) {
        float lf = (lacc4[st][0] + lacc4[st][1]) + (lacc4[st][2] + lacc4[st][3]);
        lf += __shfl_xor(lf, 16);
        lf += __shfl_xor(lf, 32);
        const float rl = 1.f / lf;               // lane-local: s = l15-based
        const int s = sblk + wv * 32 + st * 16 + l15;
        u16t* zrow = zT + ((long)b * 1024 + s) * 256 + h * 32;
        const uint2 u0 = f2bf_pk4(zacc[st][0][0] * rl, zacc[st][0][1] * rl,
                                  zacc[st][0][2] * rl, zacc[st][0][3] * rl);
        *(uint2*)(zrow + quad * 4) = u0;
        const uint2 u1 = f2bf_pk4(zacc[st][1][0] * rl, zacc[st][1][1] * rl,
                                  zacc[st][1][2] * rl, zacc[st][1][3] * rl);
        *(uint2*)(zrow + 16 + quad * 4) = u1;
    }
}

// ---------------------------------------------------------------------------
// Fused output GEMM (R2/R3 config): out = w_o @ z + w_res @ x + biases.
// Block = 64 o x 64 l; 4 waves = 2x2; wave = 32 o x 32 l (4 acc chains).
// ---------------------------------------------------------------------------
__global__ __launch_bounds__(256) void out_gemm_kernel(
    const u16t* __restrict__ wob, const u16t* __restrict__ wrb,
    const u16t* __restrict__ zT, const u16t* __restrict__ xbT,
    const float* __restrict__ b_o, const float* __restrict__ b_res,
    float* __restrict__ out)
{
    const int lblk = blockIdx.x * 64, oblk = blockIdx.y * 64, b = blockIdx.z;
    const int tid = threadIdx.x, lane = tid & 63, wv = tid >> 6;
    const int wm = wv >> 1, wn = wv & 1;
    const int l15 = lane & 15, quad = lane >> 4;
    const int ow = oblk + wm * 32;
    const int lw = lblk + wn * 32;

    f32x4 acc[2][2];
#pragma unroll
    for (int a = 0; a < 2; a++)
#pragma unroll
        for (int c = 0; c < 2; c++) acc[a][c] = (f32x4)0.f;

#pragma unroll
    for (int ks = 0; ks < 8; ks++) {           // z part, K=256
        const int k0 = ks * 32 + quad * 8;
        const bf16x8 af0 = *(const bf16x8*)(wob + (ow + l15) * 256 + k0);
        const bf16x8 af1 = *(const bf16x8*)(wob + (ow + 16 + l15) * 256 + k0);
        const bf16x8 bf0 = *(const bf16x8*)(zT + ((long)b * 1024 + lw + l15) * 256 + k0);
        const bf16x8 bf1 = *(const bf16x8*)(zT + ((long)b * 1024 + lw + 16 + l15) * 256 + k0);
        acc[0][0] = __builtin_amdgcn_mfma_f32_16x16x32_bf16(af0, bf0, acc[0][0], 0, 0, 0);
        acc[0][1] = __builtin_amdgcn_mfma_f32_16x16x32_bf16(af0, bf1, acc[0][1], 0, 0, 0);
        acc[1][0] = __builtin_amdgcn_mfma_f32_16x16x32_bf16(af1, bf0, acc[1][0], 0, 0, 0);
        acc[1][1] = __builtin_amdgcn_mfma_f32_16x16x32_bf16(af1, bf1, acc[1][1], 0, 0, 0);
    }
#pragma unroll
    for (int ks = 0; ks < 4; ks++) {           // x part, K=128
        const int k0 = ks * 32 + quad * 8;
        const bf16x8 af0 = *(const bf16x8*)(wrb + (ow + l15) * 128 + k0);
        const bf16x8 af1 = *(const bf16x8*)(wrb + (ow + 16 + l15) * 128 + k0);
        const bf16x8 bf0 = *(const bf16x8*)(xbT + ((long)b * 1024 + lw + l15) * 128 + k0);
        const bf16x8 bf1 = *(const bf16x8*)(xbT + ((long)b * 1024 + lw + 16 + l15) * 128 + k0);
        acc[0][0] = __builtin_amdgcn_mfma_f32_16x16x32_bf16(af0, bf0, acc[0][0], 0, 0, 0);
        acc[0][1] = __builtin_amdgcn_mfma_f32_16x16x32_bf16(af0, bf1, acc[0][1], 0, 0, 0);
        acc[1][0] = __builtin_amdgcn_mfma_f32_16x16x32_bf16(af1, bf0, acc[1][0], 0, 0, 0);
        acc[1][1] = __builtin_amdgcn_mfma_f32_16x16x32_bf16(af1, bf1, acc[1][1], 0, 0, 0);
    }

#pragma unroll
    for (int mi = 0; mi < 2; mi++) {
#pragma unroll
        for (int r = 0; r < 4; r++) {
            const int o = ow + mi * 16 + quad * 4 + r;
            const float bias = b_o[o] + b_res[o];
#pragma unroll
            for (int ni = 0; ni < 2; ni++)
                out[((long)b * 128 + o) * 1024 + lw + ni * 16 + l15] = acc[mi][ni][r] + bias;
        }
    }
}

// ---------------------------------------------------------------------------
extern "C" void kernel_launch(void* const* d_in, const int* in_sizes, int n_in,
                              void* d_out, int out_size, void* d_ws, size_t ws_size,
                              hipStream_t stream)
{
    const float* x     = (const float*)d_in[0];
    const float* w_qkv = (const float*)d_in[1];
    const float* b_qkv = (const float*)d_in[2];
    const float* w_o   = (const float*)d_in[3];
    const float* b_o   = (const float*)d_in[4];
    const float* w_res = (const float*)d_in[5];
    const float* b_res = (const float*)d_in[6];
    float* out = (float*)d_out;

    u16t* xbT = (u16t*)d_ws;                   // [B][1024][128]
    u16t* qT  = xbT + (size_t)2097152;         // [B][H][1024][32]
    u16t* kT  = qT  + (size_t)4194304;         // [B][H][1024][32]
    u16t* vN  = kT  + (size_t)4194304;         // [B][H][32][1024]
    u16t* zT  = vN  + (size_t)4194304;         // [B][1024][256]
    u16t* wqb = zT  + (size_t)4194304;         // [768][128]
    u16t* wob = wqb + (size_t)98304;           // [128][256]
    u16t* wrb = wob + (size_t)32768;           // [128][128]

    prep_kernel<<<dim3(16, 16, 2), 256, 0, stream>>>(x, w_qkv, w_o, w_res, xbT, wqb, wob, wrb);
    qkv_gemm_kernel<<<dim3(8, 128, 1), 256, 0, stream>>>(wqb, xbT, b_qkv, qT, kT, vN);
    attn_kernel5<<<dim3(128, 8, 1), 256, 0, stream>>>(qT, kT, vN, zT);
    out_gemm_kernel<<<dim3(16, 2, 16), 256, 0, stream>>>(wob, wrb, zT, xbT, b_o, b_res, out);
}